// Round 18
// baseline (44.782 us; speedup 1.0000x reference)
//
#include <hip/hip_runtime.h>

// CondConv2d B=16,CIN=COUT=128,H=W=56,E=4,3x3,pad=1 fp32.
// (1) mix: fold routing into bf16 Wmix[b][cc][tap][co][ci_l] (conv linear in W).
// (2) conv: block=(b, h-pair, px-half): 128co x 64px x K=1152 GEMM on
//     mfma_32x32x16_bf16. 896 blocks x 4 waves (wave 64co x 32px — champion
//     microstructure byte-identical) -> 3 blocks/CU, 12 waves/CU, 3.5
//     blocks/CU demand (load-balance quantization 1/3.5 vs 1/1.75).
//     A: global_load_lds 4-slab counted-vmcnt rotation (2 DMA/thread/slab).
//     B: x staged fp32->bf16 per ci-chunk, 34 cols x 72B stride.

typedef float  f32x16 __attribute__((ext_vector_type(16)));
typedef short  s16x8  __attribute__((ext_vector_type(8)));
typedef unsigned short u16;

#define CIN   128
#define COUT  128
#define HH    56
#define WW    56
#define SP    (HH*WW)          // 3136
#define EW    147456           // per-expert W elems
#define BW_   147456           // per-sample Wmix elems: [cc4][tap9][co128][ci32]
#define XSTR  72               // xbuf col stride bytes (64 data + 8 pad)
#define XB2   (4*34*XSTR)      // 9792 B: 4 rows x 34 cols x 32ci bf16
#define AB    8192             // one A slab: 128 co x 32 ci bf16

static __device__ __forceinline__ u16 f2bf(float f) {
    unsigned u = __builtin_bit_cast(unsigned, f);
    return (u16)((u + 0x7FFFu + ((u >> 16) & 1u)) >> 16);
}

static __device__ __forceinline__ void gload16(const void* g, void* l) {
    __builtin_amdgcn_global_load_lds(
        (const __attribute__((address_space(1))) void*)g,
        (__attribute__((address_space(3))) void*)l, 16, 0, 0);
}

// ---------------------------------------------------------------------------
// mix v2: Wmix[b][cc][tap][co][ci_l] = sum_e r[b,e]*W[e][co][ci][tap]
// thread=(co,ci): contiguous 36B reads per expert; grid.y = 4 b-quads.
// ---------------------------------------------------------------------------
__global__ __launch_bounds__(256) void mix_kernel(const float* __restrict__ W,
                                                  const float* __restrict__ r,
                                                  u16* __restrict__ Wmix) {
    const int o  = blockIdx.x * 256 + threadIdx.x;   // [0, 16384) = (co, ci)
    const int ci = o & 127;
    const int co = o >> 7;
    const int cc   = ci >> 5;
    const int ci_l = ci & 31;
    const int bq   = blockIdx.y;

    float wv[4][9];
    const float* src = W + ((size_t)co * CIN + ci) * 9;
    #pragma unroll
    for (int e = 0; e < 4; ++e)
        #pragma unroll
        for (int tap = 0; tap < 9; ++tap)
            wv[e][tap] = src[(size_t)e * EW + tap];

    #pragma unroll
    for (int bb = 0; bb < 4; ++bb) {
        const int b = bq * 4 + bb;
        const float r0 = r[b*4+0], r1 = r[b*4+1], r2 = r[b*4+2], r3 = r[b*4+3];
        #pragma unroll
        for (int tap = 0; tap < 9; ++tap) {
            float acc = r0*wv[0][tap] + r1*wv[1][tap]
                      + r2*wv[2][tap] + r3*wv[3][tap];
            Wmix[(size_t)b * BW_ + (((cc*9 + tap)*128 + co) << 5) + ci_l] = f2bf(acc);
        }
    }
}

// ---------------------------------------------------------------------------
// conv. LDS: xbuf 9792 + 4 A slabs 32768 = 42560 B -> 3 blocks/CU (12 w/CU).
// ---------------------------------------------------------------------------
__global__ __launch_bounds__(256, 3) void conv_mfma(const float* __restrict__ x,
                                                    const u16* __restrict__ Wmix,
                                                    float* __restrict__ out) {
    __shared__ __align__(16) char ldsb[XB2 + 4*AB];

    const int bid = blockIdx.x;
    const int bs  = (bid & 7) * 112 + (bid >> 3);    // bijective XCD swizzle (896=8*112)
    const int b   = bs / 56;
    const int rem = bs % 56;
    const int ph  = rem >> 1;                        // rows {2ph, 2ph+1}
    const int pxh = rem & 1;                         // px half: cols [pxh*32, +32)
    const int w0  = pxh * 32;
    const int t    = threadIdx.x;
    const int lane = t & 63;
    const int wid  = t >> 6;                         // 0..3
    const int wm   = wid >> 1;                       // co half
    const int wn   = wid & 1;                        // output row within pair
    const int l31  = lane & 31;
    const int khalf= lane >> 5;

    const u16*   WmixB = Wmix + (size_t)b * BW_;
    const float* xbB   = x + (size_t)b * CIN * SP;

    // A DMA: two rounds r: slot=(r*256+t), row=slot>>2 (0..127), 16B dest slot
    // (slot&3), src slot inverse-swizzled ((row>>1)&3 == (t>>3)&3 both rounds).
    const int ssl = (t & 3) ^ ((t >> 3) & 3);

    f32x16 acc[2];
    acc[0] = (f32x16)0.f;
    acc[1] = (f32x16)0.f;

    auto stageA = [&](int it) {
        char* base = ldsb + XB2 + (it & 3) * AB;
        const u16* ga = WmixB + it * 4096 + (t >> 2) * 32 + ssl * 8;
        gload16(ga,        base + wid * 1024);           // rows 0..63
        gload16(ga + 2048, base + 4096 + wid * 1024);    // rows 64..127
    };

    // B staging: xbuf[row 0..3][col 0..33][32 ci]; col c -> input w = w0+c-1.
    auto stageX = [&](int cc) {
        #pragma unroll
        for (int i = 0; i < 3; ++i) {
            int s = i * 256 + t;                     // 0..767 (need 544)
            if (s < 544) {
                int c    = s % 34;
                int rest = s / 34;                   // 0..15
                int row  = rest & 3;
                int g    = rest >> 2;                // ci group 0..3
                int rr   = 2*ph - 1 + row;
                int w    = w0 + c - 1;
                bool ok  = ((unsigned)rr < 56u) && ((unsigned)w < 56u);
                const float* p = xbB + (size_t)(cc*32 + g*8) * SP + rr*56 + w;
                s16x8 v;
                #pragma unroll
                for (int j = 0; j < 8; ++j) {
                    float f = ok ? p[(size_t)j * SP] : 0.f;
                    v[j] = (short)f2bf(f);
                }
                *(s16x8*)(ldsb + (row*34 + c)*XSTR + g*16) = v;
            }
        }
    };

    auto compute = [&](int it, int kh, int kw) {
        const char* Ab = ldsb + XB2 + (it & 3) * AB;
        #pragma unroll
        for (int ksub = 0; ksub < 2; ++ksub) {
            const int s = ksub * 2 + khalf;
            s16x8 af[2], bv;
            #pragma unroll
            for (int mf = 0; mf < 2; ++mf)
                af[mf] = *(const s16x8*)(Ab + (wm*64 + mf*32 + l31)*64
                                            + ((s ^ ((l31 >> 1) & 3)) * 16));
            const int c = l31 + kw;                  // 0..33
            bv = *(const s16x8*)(ldsb + ((wn + kh)*34 + c)*XSTR + s*16);
            #pragma unroll
            for (int mf = 0; mf < 2; ++mf)
                acc[mf] = __builtin_amdgcn_mfma_f32_32x32x16_bf16(
                    af[mf], bv, acc[mf], 0, 0, 0);
        }
    };

    // --- prologue: A slabs 0,1; x chunk 0 ---
    stageA(0);
    stageA(1);
    stageX(0);
    asm volatile("s_waitcnt lgkmcnt(0)" ::: "memory");
    __builtin_amdgcn_sched_barrier(0);
    __builtin_amdgcn_s_barrier();                    // slabs fly; xbuf(0) visible
    __builtin_amdgcn_sched_barrier(0);

    #pragma unroll
    for (int cc = 0; cc < 4; ++cc) {
        if (cc) {
            __builtin_amdgcn_sched_barrier(0);
            __builtin_amdgcn_s_barrier();            // all waves done reading xbuf
            __builtin_amdgcn_sched_barrier(0);
            stageX(cc);
            asm volatile("s_waitcnt lgkmcnt(0)" ::: "memory");
            __builtin_amdgcn_sched_barrier(0);
            __builtin_amdgcn_s_barrier();            // xbuf writes visible
            __builtin_amdgcn_sched_barrier(0);
        }
        #pragma unroll
        for (int tap = 0; tap < 9; ++tap) {
            const int it = cc * 9 + tap;
            if (it + 2 < 36) {
                stageA(it + 2);                      // 2 DMA instr per thread
                asm volatile("s_waitcnt vmcnt(4)" ::: "memory");  // slab it landed
            } else if (it + 1 < 36) {
                asm volatile("s_waitcnt vmcnt(2)" ::: "memory");
            } else {
                asm volatile("s_waitcnt vmcnt(0)" ::: "memory");
            }
            __builtin_amdgcn_s_barrier();
            __builtin_amdgcn_sched_barrier(0);
            __builtin_amdgcn_s_setprio(1);
            compute(it, tap / 3, tap % 3);
            __builtin_amdgcn_s_setprio(0);
        }
    }

    // store: D col(px)=l31, row(co) = (reg&3) + 8*(reg>>2) + 4*khalf
    const int w = w0 + l31;
    if (w < 56) {
        const int hrow = 2 * ph + wn;
        #pragma unroll
        for (int mf = 0; mf < 2; ++mf) {
            #pragma unroll
            for (int rg = 0; rg < 16; ++rg) {
                int co = wm*64 + mf*32 + (rg & 3) + 8*(rg >> 2) + 4*khalf;
                out[(((size_t)b*COUT + co)*HH + hrow)*WW + w] = acc[mf][rg];
            }
        }
    }
}

extern "C" void kernel_launch(void* const* d_in, const int* in_sizes, int n_in,
                              void* d_out, int out_size, void* d_ws, size_t ws_size,
                              hipStream_t stream) {
    const float* x = (const float*)d_in[0];          // [16,128,56,56]
    const float* r = (const float*)d_in[1];          // [16,4]
    const float* W = (const float*)d_in[2];          // [4,128,128,3,3]
    float* outp = (float*)d_out;                     // [16,128,56,56]
    u16* Wmix = (u16*)d_ws;                          // 4.72 MB

    mix_kernel<<<dim3(64, 4), 256, 0, stream>>>(W, r, Wmix);
    conv_mfma <<<896, 256, 0, stream>>>(x, Wmix, outp);
}

// Round 19
// 34.323 us; speedup vs baseline: 1.3047x; 1.3047x over previous
//
#include <hip/hip_runtime.h>

// CondConv2d B=16,CIN=COUT=128,H=W=56,E=4,3x3,pad=1 fp32.
// FINAL (champion, R17 = best measured 34.41 us):
// (1) mix v2: fold routing into bf16 Wmix[b][cc][tap][co][ci_l] (conv linear
//     in W); thread=(co,ci) reads contiguous, writes wave-contiguous.
// (2) conv (R11 champion): block=(b,h-pair): 128co x 128px x K=1152 GEMM on
//     mfma_32x32x16_bf16, 512 thr / 8 waves (wm x wn x wp), 16 waves/CU.
//     A: global_load_lds 4-slab counted-vmcnt rotation (DMA cannot be sunk
//     by the compiler; counted vmcnt keeps 2 slabs in flight across barriers).
//     B: x staged fp32->bf16 in LDS once per ci-chunk, 72B row stride
//     (~2-way banks = free). 36 windows {stageA(it+2); vmcnt(2); barrier;
//     setprio(1) 6 ds_read_b128 + 4 MFMA setprio(0)}.

typedef float  f32x16 __attribute__((ext_vector_type(16)));
typedef short  s16x8  __attribute__((ext_vector_type(8)));
typedef unsigned short u16;

#define CIN   128
#define COUT  128
#define HH    56
#define WW    56
#define SP    (HH*WW)          // 3136
#define EW    147456           // per-expert W elems
#define BW_   147456           // per-sample Wmix elems: [cc4][tap9][co128][ci32]
#define XSTR  72               // xbuf row stride bytes (64 data + 8 pad)
#define XB    (4*66*XSTR)      // 19008 B
#define AB    8192             // one A slab: 128 co x 32 ci bf16

static __device__ __forceinline__ u16 f2bf(float f) {
    unsigned u = __builtin_bit_cast(unsigned, f);
    return (u16)((u + 0x7FFFu + ((u >> 16) & 1u)) >> 16);
}

static __device__ __forceinline__ void gload16(const void* g, void* l) {
    __builtin_amdgcn_global_load_lds(
        (const __attribute__((address_space(1))) void*)g,
        (__attribute__((address_space(3))) void*)l, 16, 0, 0);
}

// ---------------------------------------------------------------------------
// mix v2: Wmix[b][cc][tap][co][ci_l] = sum_e r[b,e]*W[e][co][ci][tap]
// thread o = (co,ci): reads W[e][co][ci][0..8] contiguous (36B) per expert;
// grid.y = 4 b-quads (W re-read 4x, L2-resident). Writes wave-contiguous.
// ---------------------------------------------------------------------------
__global__ __launch_bounds__(256) void mix_kernel(const float* __restrict__ W,
                                                  const float* __restrict__ r,
                                                  u16* __restrict__ Wmix) {
    const int o  = blockIdx.x * 256 + threadIdx.x;   // [0, 16384) = (co, ci)
    const int ci = o & 127;
    const int co = o >> 7;
    const int cc   = ci >> 5;
    const int ci_l = ci & 31;
    const int bq   = blockIdx.y;                     // b-quad

    float wv[4][9];
    const float* src = W + ((size_t)co * CIN + ci) * 9;
    #pragma unroll
    for (int e = 0; e < 4; ++e)
        #pragma unroll
        for (int tap = 0; tap < 9; ++tap)
            wv[e][tap] = src[(size_t)e * EW + tap];

    #pragma unroll
    for (int bb = 0; bb < 4; ++bb) {
        const int b = bq * 4 + bb;
        const float r0 = r[b*4+0], r1 = r[b*4+1], r2 = r[b*4+2], r3 = r[b*4+3];
        #pragma unroll
        for (int tap = 0; tap < 9; ++tap) {
            float acc = r0*wv[0][tap] + r1*wv[1][tap]
                      + r2*wv[2][tap] + r3*wv[3][tap];
            Wmix[(size_t)b * BW_ + (((cc*9 + tap)*128 + co) << 5) + ci_l] = f2bf(acc);
        }
    }
}

// ---------------------------------------------------------------------------
// conv (R11 champion). LDS: xbuf 19008 + 4 A slabs 32768 = 51776 B.
// ---------------------------------------------------------------------------
__global__ __launch_bounds__(512, 4) void conv_mfma(const float* __restrict__ x,
                                                    const u16* __restrict__ Wmix,
                                                    float* __restrict__ out) {
    __shared__ __align__(16) char ldsb[XB + 4*AB];

    const int bid = blockIdx.x;
    const int bs  = (bid & 7) * 56 + (bid >> 3);     // bijective XCD swizzle (448=8*56)
    const int b   = bs / 28;
    const int ph  = bs % 28;                         // rows {2ph, 2ph+1}
    const int t    = threadIdx.x;
    const int lane = t & 63;
    const int wid  = t >> 6;                         // 0..7
    const int wm   = (wid >> 2) & 1;                 // co half
    const int wn   = (wid >> 1) & 1;                 // output row within pair
    const int wp   = wid & 1;                        // px half
    const int l31  = lane & 31;
    const int khalf= lane >> 5;

    const u16*   WmixB = Wmix + (size_t)b * BW_;
    const float* xbB   = x + (size_t)b * CIN * SP;

    // A DMA: lane source row = t>>2, dest slot = t&3, src slot inverse-swizzled
    const int ssl = (t & 3) ^ ((t >> 3) & 3);

    f32x16 acc[2];
    acc[0] = (f32x16)0.f;
    acc[1] = (f32x16)0.f;

    auto stageA = [&](int it) {
        char* ldst = ldsb + XB + (it & 3) * AB + wid * 1024;
        const u16* ga = WmixB + it * 4096 + (t >> 2) * 32 + ssl * 8;
        gload16(ga, ldst);
    };

    // B staging: xbuf[row 0..3][col 0..65][32 ci] bf16 for ci-chunk cc
    auto stageX = [&](int cc) {
        #pragma unroll
        for (int i = 0; i < 2; ++i) {
            int slot = i * 512 + t;                  // 0..1023
            int c    = 1 + (slot & 63);              // col 1..64
            int row  = (slot >> 6) & 3;              // 0..3
            int g    = slot >> 8;                    // ci group 0..3
            int rr   = 2*ph - 1 + row;               // input row
            int w    = c - 1;
            bool ok  = ((unsigned)rr < 56u) && (w < 56);
            const float* p = xbB + (size_t)(cc*32 + g*8) * SP + rr*56 + w;
            s16x8 v;
            #pragma unroll
            for (int j = 0; j < 8; ++j) {
                float f = ok ? p[(size_t)j * SP] : 0.f;
                v[j] = (short)f2bf(f);
            }
            *(s16x8*)(ldsb + (row*66 + c)*XSTR + g*16) = v;
        }
    };

    auto compute = [&](int it, int kh, int kw) {
        const char* Ab = ldsb + XB + (it & 3) * AB;
        #pragma unroll
        for (int ksub = 0; ksub < 2; ++ksub) {
            const int s = ksub * 2 + khalf;
            s16x8 af[2], bv;
            #pragma unroll
            for (int mf = 0; mf < 2; ++mf)
                af[mf] = *(const s16x8*)(Ab + (wm*64 + mf*32 + l31)*64
                                            + ((s ^ ((l31 >> 1) & 3)) * 16));
            const int c = wp*32 + l31 + kw;          // 0..65
            bv = *(const s16x8*)(ldsb + ((wn + kh)*66 + c)*XSTR + s*16);
            #pragma unroll
            for (int mf = 0; mf < 2; ++mf)
                acc[mf] = __builtin_amdgcn_mfma_f32_32x32x16_bf16(
                    af[mf], bv, acc[mf], 0, 0, 0);
        }
    };

    // --- prologue: zero halo cols (c=0,65); A slabs 0,1; x chunk 0 ---
    if (t < 32) {
        int row = t >> 3, col = ((t >> 2) & 1) ? 65 : 0, sl = t & 3;
        *(s16x8*)(ldsb + (row*66 + col)*XSTR + sl*16) = (s16x8)0;
    }
    stageA(0);
    stageA(1);
    stageX(0);
    asm volatile("s_waitcnt lgkmcnt(0)" ::: "memory");
    __builtin_amdgcn_sched_barrier(0);
    __builtin_amdgcn_s_barrier();                    // slabs fly; xbuf(0) visible
    __builtin_amdgcn_sched_barrier(0);

    #pragma unroll
    for (int cc = 0; cc < 4; ++cc) {
        if (cc) {
            __builtin_amdgcn_sched_barrier(0);
            __builtin_amdgcn_s_barrier();            // all waves done reading xbuf
            __builtin_amdgcn_sched_barrier(0);
            stageX(cc);
            asm volatile("s_waitcnt lgkmcnt(0)" ::: "memory");
            __builtin_amdgcn_sched_barrier(0);
            __builtin_amdgcn_s_barrier();            // xbuf writes visible
            __builtin_amdgcn_sched_barrier(0);
        }
        #pragma unroll
        for (int tap = 0; tap < 9; ++tap) {
            const int it = cc * 9 + tap;
            if (it + 2 < 36) {
                stageA(it + 2);                      // 1 DMA instr per wave
                asm volatile("s_waitcnt vmcnt(2)" ::: "memory");  // it's slab landed
            } else if (it + 1 < 36) {
                asm volatile("s_waitcnt vmcnt(1)" ::: "memory");
            } else {
                asm volatile("s_waitcnt vmcnt(0)" ::: "memory");
            }
            __builtin_amdgcn_s_barrier();
            __builtin_amdgcn_sched_barrier(0);
            __builtin_amdgcn_s_setprio(1);
            compute(it, tap / 3, tap % 3);
            __builtin_amdgcn_s_setprio(0);
        }
    }

    // store: D col(px)=l31, row(co) = (reg&3) + 8*(reg>>2) + 4*khalf
    const int w = wp * 32 + l31;
    if (w < 56) {
        const int hrow = 2 * ph + wn;
        #pragma unroll
        for (int mf = 0; mf < 2; ++mf) {
            #pragma unroll
            for (int rg = 0; rg < 16; ++rg) {
                int co = wm*64 + mf*32 + (rg & 3) + 8*(rg >> 2) + 4*khalf;
                out[(((size_t)b*COUT + co)*HH + hrow)*WW + w] = acc[mf][rg];
            }
        }
    }
}

extern "C" void kernel_launch(void* const* d_in, const int* in_sizes, int n_in,
                              void* d_out, int out_size, void* d_ws, size_t ws_size,
                              hipStream_t stream) {
    const float* x = (const float*)d_in[0];          // [16,128,56,56]
    const float* r = (const float*)d_in[1];          // [16,4]
    const float* W = (const float*)d_in[2];          // [4,128,128,3,3]
    float* outp = (float*)d_out;                     // [16,128,56,56]
    u16* Wmix = (u16*)d_ws;                          // 4.72 MB

    mix_kernel<<<dim3(64, 4), 256, 0, stream>>>(W, r, Wmix);
    conv_mfma <<<448, 512, 0, stream>>>(x, Wmix, outp);
}